// Round 3
// baseline (319.336 us; speedup 1.0000x reference)
//
#include <hip/hip_runtime.h>
#include <stdint.h>

typedef unsigned short u16;
typedef unsigned int   u32;

#define BB 16
#define CC 256
#define NN 4096
#define KK 128

// workspace layout (float offsets into W = (float*)d_ws)
#define OFF_M1   0        // 32768 floats: M1[c][k] = sum_d w1[d,c]*mk[d,k]
#define OFF_M2   32768    // 32768 floats: M2[d][k] = sum_c w2[d,c]*mk[c,k]
#define OFF_BK   65536    // 128 floats : biask[k] = sum_d b1[d]*mk[d,k]
#define OFF_S    65664    // 2048 floats: s[b][k] = sum_n exp(logit)
#define OFF_BN   67712    // 8 replicas * 512 floats (256 sum + 256 sumsq)
#define OFF_SC   71808    // 256 floats scale
#define OFF_SH   72064    // 256 floats shift
#define OFF_P_BYTES (72320*4)   // p = exp(logit), bf16 [B][N][K], 16.78 MB

__device__ __forceinline__ float bf2f(u16 h) {
  union { u32 u; float f; } v; v.u = ((u32)h) << 16; return v.f;
}
__device__ __forceinline__ u16 f2bf(float f) {
  union { float f; u32 u; } v; v.f = f;
  u32 r = (v.u + 0x7FFFu + ((v.u >> 16) & 1u)) >> 16;
  return (u16)r;
}

// ---------------- K0: precompute M1, M2, biask; zero atomic accumulators ----
__global__ __launch_bounds__(256) void k0_pre(
    const float* __restrict__ w1, const float* __restrict__ b1,
    const float* __restrict__ mk, const float* __restrict__ w2,
    float* __restrict__ W)
{
  int g = blockIdx.x * 256 + threadIdx.x;
  if (g < 32768) {
    int c = g >> 7, k = g & 127;
    float s = 0.f;
#pragma unroll 8
    for (int d = 0; d < 256; ++d)
      s = fmaf(w1[d*256 + c], mk[d*128 + k], s);
    W[OFF_M1 + g] = s;
  } else if (g < 65536) {
    int g2 = g - 32768;
    int d = g2 >> 7, k = g2 & 127;
    float s = 0.f;
#pragma unroll 8
    for (int c = 0; c < 256; ++c)
      s = fmaf(w2[d*256 + c], mk[c*128 + k], s);
    W[OFF_M2 + g2] = s;
  } else if (g < 65664) {
    int k = g - 65536;
    float s = 0.f;
#pragma unroll 8
    for (int d = 0; d < 256; ++d)
      s = fmaf(b1[d], mk[d*128 + k], s);
    W[OFF_BK + k] = s;
  } else if (g < 71808) {
    W[g] = 0.f;   // zero s[] and bn accumulators (contiguous region)
  }
}

// ---------------- K1: p = exp(x^T @ M1 + biask) ; fused sum_n exp ----------
// grid (32 n-tiles, 16 b), block 256. Tile 128n x 128k, 8x8 per thread.
__global__ __launch_bounds__(256) void k1_logits(
    const float* __restrict__ x, float* __restrict__ W,
    u16* __restrict__ p)
{
  __shared__ float xs[16][129];   // [cc][n]
  __shared__ float ms[16][129];   // [cc][k]
  __shared__ float red[16][129];  // exp partials [tyn][k]

  const float* M1 = W + OFF_M1;
  const float* biask = W + OFF_BK;
  float* s_glob = W + OFF_S;

  const int tid = threadIdx.x;
  const int b  = blockIdx.y;
  const int n0 = blockIdx.x * 128;
  const int tyn = tid >> 4;       // 0..15 (n group, strided)
  const int tx  = tid & 15;       // 0..15 (k group, blocked)
  const int scc = tid >> 4;       // staging row
  const int s8  = (tid & 15) * 8; // staging col

  float acc[8][8];
#pragma unroll
  for (int i = 0; i < 8; ++i)
#pragma unroll
    for (int j = 0; j < 8; ++j) acc[i][j] = 0.f;

  const float* xb = x + (size_t)b * CC * NN;

  for (int c0 = 0; c0 < 256; c0 += 16) {
    // stage x tile (16c x 128n f32) and M1 tile (16c x 128k f32)
    float4 a0 = *(const float4*)(xb + (size_t)(c0 + scc) * NN + n0 + s8);
    float4 a1 = *(const float4*)(xb + (size_t)(c0 + scc) * NN + n0 + s8 + 4);
    float4 m0 = *(const float4*)(M1 + (size_t)(c0 + scc) * 128 + s8);
    float4 m1 = *(const float4*)(M1 + (size_t)(c0 + scc) * 128 + s8 + 4);
    xs[scc][s8+0] = a0.x; xs[scc][s8+1] = a0.y;
    xs[scc][s8+2] = a0.z; xs[scc][s8+3] = a0.w;
    xs[scc][s8+4] = a1.x; xs[scc][s8+5] = a1.y;
    xs[scc][s8+6] = a1.z; xs[scc][s8+7] = a1.w;
    ms[scc][s8+0] = m0.x; ms[scc][s8+1] = m0.y;
    ms[scc][s8+2] = m0.z; ms[scc][s8+3] = m0.w;
    ms[scc][s8+4] = m1.x; ms[scc][s8+5] = m1.y;
    ms[scc][s8+6] = m1.z; ms[scc][s8+7] = m1.w;
    __syncthreads();
#pragma unroll 2
    for (int cc = 0; cc < 16; ++cc) {
      float av[8], bv[8];
#pragma unroll
      for (int i = 0; i < 8; ++i) av[i] = xs[cc][tyn + 16*i];
#pragma unroll
      for (int j = 0; j < 8; ++j) bv[j] = ms[cc][tx*8 + j];
#pragma unroll
      for (int i = 0; i < 8; ++i)
#pragma unroll
        for (int j = 0; j < 8; ++j)
          acc[i][j] = fmaf(av[i], bv[j], acc[i][j]);
    }
    __syncthreads();
  }

  // epilogue: bias, exp, bf16 store of p, per-k partial sums
  float bk[8];
#pragma unroll
  for (int j = 0; j < 8; ++j) bk[j] = biask[tx*8 + j];
  float pk[8];
#pragma unroll
  for (int j = 0; j < 8; ++j) pk[j] = 0.f;
#pragma unroll
  for (int i = 0; i < 8; ++i) {
    const int n = n0 + tyn + 16*i;
    u16 hh[8];
#pragma unroll
    for (int j = 0; j < 8; ++j) {
      float e = __expf(acc[i][j] + bk[j]);
      hh[j] = f2bf(e);
      pk[j] += e;
    }
    uint4 st;
    st.x = (u32)hh[0] | ((u32)hh[1] << 16);
    st.y = (u32)hh[2] | ((u32)hh[3] << 16);
    st.z = (u32)hh[4] | ((u32)hh[5] << 16);
    st.w = (u32)hh[6] | ((u32)hh[7] << 16);
    *(uint4*)(p + ((size_t)b * NN + n) * 128 + tx*8) = st;
  }
#pragma unroll
  for (int j = 0; j < 8; ++j) red[tyn][tx*8 + j] = pk[j];
  __syncthreads();
  if (tid < 128) {
    float t = 0.f;
#pragma unroll
    for (int r = 0; r < 16; ++r) t += red[r][tid];
    atomicAdd(&s_glob[b*128 + tid], t);
  }
}

// ---------------- K3: attn normalize + o3 = attn @ M2^T + b2 ; BN partials -
// grid (64 n-tiles, 2 d-tiles, 16 b), block 256. Half-K LDS tiles (<64KB).
__global__ __launch_bounds__(256) void k3_attn(
    const u16* __restrict__ p, const float* __restrict__ b2,
    float* __restrict__ W, float* __restrict__ o3)
{
  __shared__ float at[64][65];    // [n][k-half]
  __shared__ float m2s[128][65];  // [d][k-half]
  __shared__ float rs[64];        // raw row sums over k

  const float* M2 = W + OFF_M2;
  const float* s_glob = W + OFF_S;
  float* bnacc = W + OFF_BN;

  const int tid = threadIdx.x;
  const int n0 = blockIdx.x * 64;
  const int d0 = blockIdx.y * 128;
  const int b  = blockIdx.z;
  const int tdy = tid >> 4;   // d group (strided)
  const int tnx = tid & 15;   // n group (blocked)

  float acc[8][4];
#pragma unroll
  for (int i = 0; i < 8; ++i)
#pragma unroll
    for (int j = 0; j < 4; ++j) acc[i][j] = 0.f;

  for (int kh = 0; kh < 2; ++kh) {
    // stage softmax numerators: at[n][k] = p/s[b][k]
    {
      const int k = tid & 63;
      const int nh = tid >> 6;  // 0..3
      const float inv = 1.0f / s_glob[b*128 + kh*64 + k];
      const u16* lp = p + ((size_t)b*NN + n0 + nh)*128 + kh*64 + k;
#pragma unroll 4
      for (int r = 0; r < 16; ++r)
        at[nh + 4*r][k] = bf2f(lp[(size_t)(4*r)*128]) * inv;
    }
    // stage M2 half-tile
#pragma unroll 2
    for (int q = 0; q < 8; ++q) {
      int flat = (q*256 + tid) * 4;  // 0..8191
      int dd = flat >> 6;
      int kk = flat & 63;
      float4 v = *(const float4*)(M2 + (size_t)(d0 + dd)*128 + kh*64 + kk);
      m2s[dd][kk+0] = v.x; m2s[dd][kk+1] = v.y;
      m2s[dd][kk+2] = v.z; m2s[dd][kk+3] = v.w;
    }
    __syncthreads();
    // partial row sums over this k half
    if (tid < 64) {
      float t = (kh == 0) ? 0.f : rs[tid];
#pragma unroll 8
      for (int k = 0; k < 64; ++k) t += at[tid][k];
      rs[tid] = t;
    }
    // GEMM over this k half
#pragma unroll 2
    for (int k = 0; k < 64; ++k) {
      float av[8], bv[4];
#pragma unroll
      for (int i = 0; i < 8; ++i) av[i] = m2s[tdy + 16*i][k];
#pragma unroll
      for (int j = 0; j < 4; ++j) bv[j] = at[tnx*4 + j][k];
#pragma unroll
      for (int i = 0; i < 8; ++i)
#pragma unroll
        for (int j = 0; j < 4; ++j)
          acc[i][j] = fmaf(av[i], bv[j], acc[i][j]);
    }
    __syncthreads();
  }

  // epilogue: second normalization, +b2, fp32 store, BN partial stats
  float rsv[4];
#pragma unroll
  for (int j = 0; j < 4; ++j) rsv[j] = 1.0f / (1e-5f + rs[tnx*4 + j]);
  float* bs = bnacc + (size_t)(blockIdx.x & 7) * 512;
#pragma unroll
  for (int i = 0; i < 8; ++i) {
    const int d = d0 + tdy + 16*i;
    const float bb = b2[d];
    float4 vv;
    float s1 = 0.f, s2 = 0.f;
    float v0 = acc[i][0] * rsv[0] + bb;
    float v1 = acc[i][1] * rsv[1] + bb;
    float v2 = acc[i][2] * rsv[2] + bb;
    float v3 = acc[i][3] * rsv[3] + bb;
    vv.x = v0; vv.y = v1; vv.z = v2; vv.w = v3;
    s1 = v0 + v1 + v2 + v3;
    s2 = v0*v0 + v1*v1 + v2*v2 + v3*v3;
    *(float4*)(o3 + ((size_t)b*CC + d)*NN + n0 + tnx*4) = vv;
#pragma unroll
    for (int m = 1; m < 16; m <<= 1) {
      s1 += __shfl_xor(s1, m);
      s2 += __shfl_xor(s2, m);
    }
    if (tnx == 0) {
      atomicAdd(&bs[d], s1);
      atomicAdd(&bs[256 + d], s2);
    }
  }
}

// ---------------- K4: finalize BN scale/shift -------------------------------
__global__ __launch_bounds__(256) void k4_fin(
    const float* __restrict__ gamma, const float* __restrict__ beta,
    float* __restrict__ W)
{
  const float* bnacc = W + OFF_BN;
  int d = threadIdx.x;
  float s1 = 0.f, s2 = 0.f;
#pragma unroll
  for (int r = 0; r < 8; ++r) { s1 += bnacc[r*512 + d]; s2 += bnacc[r*512 + 256 + d]; }
  const float invn = 1.0f / 65536.0f;
  float mean = s1 * invn;
  float var = s2 * invn - mean * mean;
  float sc = gamma[d] * rsqrtf(var + 1e-3f);
  W[OFF_SC + d] = sc;
  W[OFF_SH + d] = beta[d] - mean * sc;
}

// ---------------- K5: BN apply + residual + LeakyReLU (in-place on d_out) --
__global__ __launch_bounds__(256) void k5_out(
    const float* __restrict__ x, const float* __restrict__ W,
    float* __restrict__ out)
{
  const float* scale = W + OFF_SC;
  const float* shift = W + OFF_SH;
  size_t gid = ((size_t)blockIdx.x * 256 + threadIdx.x) * 4;
  const int d = (int)((gid >> 12) & 255);
  const float sc = scale[d], sh = shift[d];
  float4 o = *(const float4*)(out + gid);     // o3 stored in d_out (fp32)
  float4 xv = *(const float4*)(x + gid);
  float v0 = fmaf(o.x, sc, sh) + xv.x;
  float v1 = fmaf(o.y, sc, sh) + xv.y;
  float v2 = fmaf(o.z, sc, sh) + xv.z;
  float v3 = fmaf(o.w, sc, sh) + xv.w;
  v0 = (v0 >= 0.f) ? v0 : 0.2f * v0;
  v1 = (v1 >= 0.f) ? v1 : 0.2f * v1;
  v2 = (v2 >= 0.f) ? v2 : 0.2f * v2;
  v3 = (v3 >= 0.f) ? v3 : 0.2f * v3;
  float4 st; st.x = v0; st.y = v1; st.z = v2; st.w = v3;
  *(float4*)(out + gid) = st;
}

extern "C" void kernel_launch(void* const* d_in, const int* in_sizes, int n_in,
                              void* d_out, int out_size, void* d_ws, size_t ws_size,
                              hipStream_t stream)
{
  const float* x  = (const float*)d_in[0];
  const float* w1 = (const float*)d_in[1];
  const float* b1 = (const float*)d_in[2];
  const float* mk = (const float*)d_in[3];
  const float* w2 = (const float*)d_in[4];
  const float* b2 = (const float*)d_in[5];
  const float* gamma = (const float*)d_in[6];
  const float* beta  = (const float*)d_in[7];

  float* W = (float*)d_ws;
  u16* p = (u16*)((char*)d_ws + OFF_P_BYTES);  // exp(logits) bf16 [B][N][K]
  float* o3 = (float*)d_out;   // fp32 [B][C][N] lives in d_out until K5 rewrites in place
  float* out = (float*)d_out;

  k0_pre<<<dim3(281), dim3(256), 0, stream>>>(w1, b1, mk, w2, W);
  k1_logits<<<dim3(32, 16), dim3(256), 0, stream>>>(x, W, p);
  k3_attn<<<dim3(64, 2, 16), dim3(256), 0, stream>>>(p, b2, W, o3);
  k4_fin<<<dim3(1), dim3(256), 0, stream>>>(gamma, beta, W);
  k5_out<<<dim3(16384), dim3(256), 0, stream>>>(x, W, out);
}

// Round 4
// 275.802 us; speedup vs baseline: 1.1578x; 1.1578x over previous
//
#include <hip/hip_runtime.h>
#include <stdint.h>

typedef unsigned short u16;
typedef unsigned int   u32;
typedef __bf16 bf16_t;
typedef bf16_t bf16x8 __attribute__((ext_vector_type(8)));
typedef float  f32x4  __attribute__((ext_vector_type(4)));

#define BB 16
#define CC 256
#define NN 4096
#define KK 128

// workspace layout (float offsets into W = (float*)d_ws)
#define OFF_M2B  0        // 32768 f: M2B[d][k] = sum_c w2[d,c]*mk[c,k] (fp32)
#define OFF_BK   32768    // 128 f  : biask[k] = sum_d b1[d]*mk[d,k]
#define OFF_S    32896    // 2048 f : s[b][k] (zeroed by K0)
#define OFF_BN   34944    // 16 replicas * 512 f (zeroed by K0)
#define OFF_SC   43136    // 256 f
#define OFF_SH   43392    // 256 f
#define OFF_RN   43648    // 65536 f: rn[b][n] = 1/(1e-5 + rowsum)
#define WS_F_END 109184
#define OFF_M1P_BYTES  (109184*4)                 // M1P[k][c] bf16, 64 KB
#define OFF_M2S_BYTES  (OFF_M1P_BYTES + 65536)    // M2s[b][d][k] bf16, 1 MB
#define OFF_P_BYTES    (OFF_M2S_BYTES + 1048576)  // p bf16 [B][N][K], 16.78 MB

__device__ __forceinline__ float bf2f(u16 h) {
  union { u32 u; float f; } v; v.u = ((u32)h) << 16; return v.f;
}
__device__ __forceinline__ u16 f2bf(float f) {
  union { float f; u32 u; } v; v.f = f;
  u32 r = (v.u + 0x7FFFu + ((v.u >> 16) & 1u)) >> 16;
  return (u16)r;
}

union BF8 { u16 u[8]; bf16x8 v; };

// ---------------- K0: M1P (bf16 packed), M2B, biask; zero s/bn --------------
__global__ __launch_bounds__(256) void k0_pre(
    const float* __restrict__ w1, const float* __restrict__ b1,
    const float* __restrict__ mk, const float* __restrict__ w2,
    float* __restrict__ W)
{
  u16* M1P = (u16*)((char*)W + OFF_M1P_BYTES);
  int g = blockIdx.x * 256 + threadIdx.x;
  if (g < 32768) {
    int k = g >> 8, c = g & 255;   // M1P[k][c] = sum_d w1[d,c]*mk[d,k]
    float s = 0.f;
#pragma unroll 8
    for (int d = 0; d < 256; ++d)
      s = fmaf(w1[d*256 + c], mk[d*128 + k], s);
    M1P[g] = f2bf(s);
  } else if (g < 65536) {
    int g2 = g - 32768;
    int d = g2 >> 7, k = g2 & 127; // M2B[d][k] = sum_c w2[d,c]*mk[c,k]
    float s = 0.f;
#pragma unroll 8
    for (int c = 0; c < 256; ++c)
      s = fmaf(w2[d*256 + c], mk[c*128 + k], s);
    W[OFF_M2B + g2] = s;
  } else if (g < 65664) {
    int k = g - 65536;
    float s = 0.f;
#pragma unroll 8
    for (int d = 0; d < 256; ++d)
      s = fmaf(b1[d], mk[d*128 + k], s);
    W[OFF_BK + k] = s;
  } else if (g < 65664 + 10240) {
    W[OFF_S + (g - 65664)] = 0.f;  // zero s[] and bnacc (contiguous)
  }
}

// ---------------- K1: p = exp(x^T @ M1 + biask); s[b][k] = sum_n p ---------
// grid (64 n-tiles, 16 b), block 256 = 4 waves. Wave: 16 tokens x 128 k.
__global__ __launch_bounds__(256) void k1_logits(
    const float* __restrict__ x, float* __restrict__ W,
    u16* __restrict__ p)
{
  const u16* M1P = (const u16*)((char*)W + OFF_M1P_BYTES);
  const float* biask = W + OFF_BK;
  float* s_glob = W + OFF_S;

  const int tid  = threadIdx.x;
  const int wave = tid >> 6;
  const int lane = tid & 63;
  const int q    = lane >> 4;
  const int col  = lane & 15;
  const int b    = blockIdx.y;
  const int n_base = blockIdx.x * 64 + wave * 16;

  f32x4 acc[8];
#pragma unroll
  for (int t = 0; t < 8; ++t) acc[t] = (f32x4){0.f, 0.f, 0.f, 0.f};

  const float* xptr = x + (size_t)b * CC * NN + (size_t)(q * 8) * NN + n_base + col;

  for (int c0 = 0; c0 < 256; c0 += 32) {
    const float* xk = xptr + (size_t)c0 * NN;
    BF8 af;
#pragma unroll
    for (int j = 0; j < 8; ++j) af.u[j] = f2bf(xk[(size_t)j * NN]);
#pragma unroll
    for (int t = 0; t < 8; ++t) {
      bf16x8 bf = *(const bf16x8*)(M1P + (t*16 + col) * 256 + c0 + q*8);
      acc[t] = __builtin_amdgcn_mfma_f32_16x16x32_bf16(af.v, bf, acc[t], 0, 0, 0);
    }
  }

  // epilogue: bias, exp, bf16 store, per-k wave reduction + atomic
  u16* pb = p + (size_t)b * NN * KK;
#pragma unroll
  for (int t = 0; t < 8; ++t) {
    const float bk = biask[t*16 + col];
    float ps = 0.f;
#pragma unroll
    for (int r = 0; r < 4; ++r) {
      const int n = n_base + q*4 + r;
      float e = __expf(acc[t][r] + bk);
      u16 hb = f2bf(e);
      pb[(size_t)n * KK + t*16 + col] = hb;
      ps += bf2f(hb);   // accumulate the rounded value for consistency
    }
    ps += __shfl_xor(ps, 16);
    ps += __shfl_xor(ps, 32);
    if (lane < 16) atomicAdd(&s_glob[b*128 + t*16 + col], ps);
  }
}

// ---------------- K2: M2s[b][d][k] = M2B/s (bf16); rn[b][n] ----------------
__global__ __launch_bounds__(256) void k2_prep(
    const u16* __restrict__ p, float* __restrict__ W)
{
  __shared__ float sinv[128];
  u16* M2s = (u16*)((char*)W + OFF_M2S_BYTES);
  const float* s_glob = W + OFF_S;
  int g = blockIdx.x * 256 + threadIdx.x;
  int b = (g < 524288) ? (g >> 15) : ((g - 524288) >> 12);
  if (threadIdx.x < 128) sinv[threadIdx.x] = 1.0f / s_glob[b*128 + threadIdx.x];
  __syncthreads();
  if (g < 524288) {
    int rem = g & 32767;             // d*128 + k
    M2s[g] = f2bf(W[OFF_M2B + rem] * sinv[g & 127]);
  } else {
    int g2 = g - 524288;
    int n = g2 & 4095;
    const uint4* pr = (const uint4*)(p + ((size_t)b * NN + n) * KK);
    float t = 0.f;
#pragma unroll 4
    for (int kk = 0; kk < 16; ++kk) {
      uint4 v = pr[kk];
      const int k8 = kk * 8;
      t += bf2f((u16)(v.x & 0xffff)) * sinv[k8+0];
      t += bf2f((u16)(v.x >> 16))    * sinv[k8+1];
      t += bf2f((u16)(v.y & 0xffff)) * sinv[k8+2];
      t += bf2f((u16)(v.y >> 16))    * sinv[k8+3];
      t += bf2f((u16)(v.z & 0xffff)) * sinv[k8+4];
      t += bf2f((u16)(v.z >> 16))    * sinv[k8+5];
      t += bf2f((u16)(v.w & 0xffff)) * sinv[k8+6];
      t += bf2f((u16)(v.w >> 16))    * sinv[k8+7];
    }
    W[OFF_RN + b*4096 + n] = 1.0f / (1e-5f + t);
  }
}

// ---------------- K3: o3 = (p @ M2s^T)*rn + b2 ; BN partials ---------------
// grid (64 n-tiles, 16 b), block 256 = 4 waves. Wave: 256 d x 16 tokens.
__global__ __launch_bounds__(256) void k3_attn(
    const u16* __restrict__ p, const float* __restrict__ b2,
    float* __restrict__ W, float* __restrict__ o3)
{
  __shared__ float bn_lds[512];
  const u16* M2s = (const u16*)((char*)W + OFF_M2S_BYTES);
  const float* rn = W + OFF_RN;
  float* bnacc = W + OFF_BN;

  const int tid  = threadIdx.x;
  const int wave = tid >> 6;
  const int lane = tid & 63;
  const int q    = lane >> 4;
  const int col  = lane & 15;
  const int b    = blockIdx.y;
  const int n_base = blockIdx.x * 64 + wave * 16;

  bn_lds[tid] = 0.f; bn_lds[256 + tid] = 0.f;
  __syncthreads();

  f32x4 acc[16];
#pragma unroll
  for (int t = 0; t < 16; ++t) acc[t] = (f32x4){0.f, 0.f, 0.f, 0.f};

  const u16* pb  = p + ((size_t)b * NN + n_base + col) * KK;
  const u16* m2b = M2s + ((size_t)b << 15);

#pragma unroll
  for (int k0 = 0; k0 < 128; k0 += 32) {
    bf16x8 bfp = *(const bf16x8*)(pb + k0 + q*8);
#pragma unroll
    for (int t = 0; t < 16; ++t) {
      bf16x8 am = *(const bf16x8*)(m2b + (t*16 + col) * 128 + k0 + q*8);
      acc[t] = __builtin_amdgcn_mfma_f32_16x16x32_bf16(am, bfp, acc[t], 0, 0, 0);
    }
  }

  // epilogue: *rn + b2, store o3 (fp32, into d_out), BN partial sums
  const int token = n_base + col;
  const float rnv = rn[b*4096 + token];
  float* ob = o3 + (size_t)b * CC * NN;
#pragma unroll
  for (int t = 0; t < 16; ++t) {
    float4 b2v = *(const float4*)(b2 + t*16 + q*4);
    float bv[4] = {b2v.x, b2v.y, b2v.z, b2v.w};
#pragma unroll
    for (int r = 0; r < 4; ++r) {
      const int d = t*16 + q*4 + r;
      float v = fmaf(acc[t][r], rnv, bv[r]);
      ob[(size_t)d * NN + token] = v;
      float s1 = v, s2 = v * v;
      s1 += __shfl_xor(s1, 1);  s2 += __shfl_xor(s2, 1);
      s1 += __shfl_xor(s1, 2);  s2 += __shfl_xor(s2, 2);
      s1 += __shfl_xor(s1, 4);  s2 += __shfl_xor(s2, 4);
      s1 += __shfl_xor(s1, 8);  s2 += __shfl_xor(s2, 8);
      if (col == 0) {
        atomicAdd(&bn_lds[d], s1);
        atomicAdd(&bn_lds[256 + d], s2);
      }
    }
  }
  __syncthreads();
  const int rep = blockIdx.x & 15;
  atomicAdd(&bnacc[rep*512 + tid],       bn_lds[tid]);
  atomicAdd(&bnacc[rep*512 + 256 + tid], bn_lds[256 + tid]);
}

// ---------------- K4: finalize BN scale/shift ------------------------------
__global__ __launch_bounds__(256) void k4_fin(
    const float* __restrict__ gamma, const float* __restrict__ beta,
    float* __restrict__ W)
{
  const float* bnacc = W + OFF_BN;
  int d = threadIdx.x;
  float s1 = 0.f, s2 = 0.f;
#pragma unroll
  for (int r = 0; r < 16; ++r) { s1 += bnacc[r*512 + d]; s2 += bnacc[r*512 + 256 + d]; }
  const float invn = 1.0f / 65536.0f;
  float mean = s1 * invn;
  float var = s2 * invn - mean * mean;
  float sc = gamma[d] * rsqrtf(var + 1e-3f);
  W[OFF_SC + d] = sc;
  W[OFF_SH + d] = beta[d] - mean * sc;
}

// ---------------- K5: BN apply + residual + LeakyReLU (in-place on d_out) --
__global__ __launch_bounds__(256) void k5_out(
    const float* __restrict__ x, const float* __restrict__ W,
    float* __restrict__ out)
{
  const float* scale = W + OFF_SC;
  const float* shift = W + OFF_SH;
  size_t gid = ((size_t)blockIdx.x * 256 + threadIdx.x) * 4;
  const int d = (int)((gid >> 12) & 255);
  const float sc = scale[d], sh = shift[d];
  float4 o = *(const float4*)(out + gid);     // o3 stored in d_out (fp32)
  float4 xv = *(const float4*)(x + gid);
  float v0 = fmaf(o.x, sc, sh) + xv.x;
  float v1 = fmaf(o.y, sc, sh) + xv.y;
  float v2 = fmaf(o.z, sc, sh) + xv.z;
  float v3 = fmaf(o.w, sc, sh) + xv.w;
  v0 = (v0 >= 0.f) ? v0 : 0.2f * v0;
  v1 = (v1 >= 0.f) ? v1 : 0.2f * v1;
  v2 = (v2 >= 0.f) ? v2 : 0.2f * v2;
  v3 = (v3 >= 0.f) ? v3 : 0.2f * v3;
  float4 st; st.x = v0; st.y = v1; st.z = v2; st.w = v3;
  *(float4*)(out + gid) = st;
}

extern "C" void kernel_launch(void* const* d_in, const int* in_sizes, int n_in,
                              void* d_out, int out_size, void* d_ws, size_t ws_size,
                              hipStream_t stream)
{
  const float* x  = (const float*)d_in[0];
  const float* w1 = (const float*)d_in[1];
  const float* b1 = (const float*)d_in[2];
  const float* mk = (const float*)d_in[3];
  const float* w2 = (const float*)d_in[4];
  const float* b2 = (const float*)d_in[5];
  const float* gamma = (const float*)d_in[6];
  const float* beta  = (const float*)d_in[7];

  float* W = (float*)d_ws;
  u16* p = (u16*)((char*)d_ws + OFF_P_BYTES);  // exp(logits) bf16 [B][N][K]
  float* o3 = (float*)d_out;   // fp32 [B][C][N] in d_out until K5 rewrites in place
  float* out = (float*)d_out;

  k0_pre<<<dim3(297), dim3(256), 0, stream>>>(w1, b1, mk, w2, W);
  k1_logits<<<dim3(64, 16), dim3(256), 0, stream>>>(x, W, p);
  k2_prep<<<dim3(2304), dim3(256), 0, stream>>>(p, W);
  k3_attn<<<dim3(64, 16), dim3(256), 0, stream>>>(p, b2, W, o3);
  k4_fin<<<dim3(1), dim3(256), 0, stream>>>(gamma, beta, W);
  k5_out<<<dim3(16384), dim3(256), 0, stream>>>(x, W, out);
}

// Round 5
// 256.696 us; speedup vs baseline: 1.2440x; 1.0744x over previous
//
#include <hip/hip_runtime.h>
#include <stdint.h>

typedef unsigned short u16;
typedef unsigned int   u32;
typedef __bf16 bf16_t;
typedef bf16_t bf16x8 __attribute__((ext_vector_type(8)));
typedef float  f32x4  __attribute__((ext_vector_type(4)));

#define BB 16
#define CC 256
#define NN 4096
#define KK 128

// workspace layout (float offsets into W = (float*)d_ws)
#define OFF_M2B  0        // 32768 f: M2B[d][k] = sum_c w2[d,c]*mk[c,k] (fp32)
#define OFF_BK   32768    // 128 f  : biask[k] = sum_d b1[d]*mk[d,k]
#define OFF_S    32896    // 2048 f : s[b][k] (zeroed by K0)
#define OFF_BN   34944    // 16 replicas * 512 f (zeroed by K0)
#define OFF_SC   43136    // 256 f
#define OFF_SH   43392    // 256 f
#define OFF_RN   43648    // 65536 f: rn[b][n] = 1/(1e-5 + rowsum)
#define WS_F_END 109184
#define OFF_M1P_BYTES  (109184*4)                 // M1P[k][c] bf16, 64 KB
#define OFF_M2S_BYTES  (OFF_M1P_BYTES + 65536)    // M2s[b][d][k] bf16, 1 MB
#define OFF_P_BYTES    (OFF_M2S_BYTES + 1048576)  // p bf16 [B][N][K], 16.78 MB

__device__ __forceinline__ float bf2f(u16 h) {
  union { u32 u; float f; } v; v.u = ((u32)h) << 16; return v.f;
}
__device__ __forceinline__ u16 f2bf(float f) {
  union { float f; u32 u; } v; v.f = f;
  u32 r = (v.u + 0x7FFFu + ((v.u >> 16) & 1u)) >> 16;
  return (u16)r;
}

union BF8 { u16 u[8]; bf16x8 v; };

// ---------------- K0: M1P (bf16 packed), M2B, biask; zero s/bn --------------
__global__ __launch_bounds__(256) void k0_pre(
    const float* __restrict__ w1, const float* __restrict__ b1,
    const float* __restrict__ mk, const float* __restrict__ w2,
    float* __restrict__ W)
{
  u16* M1P = (u16*)((char*)W + OFF_M1P_BYTES);
  int g = blockIdx.x * 256 + threadIdx.x;
  if (g < 32768) {
    int k = g >> 8, c = g & 255;   // M1P[k][c] = sum_d w1[d,c]*mk[d,k]
    float s = 0.f;
#pragma unroll 8
    for (int d = 0; d < 256; ++d)
      s = fmaf(w1[d*256 + c], mk[d*128 + k], s);
    M1P[g] = f2bf(s);
  } else if (g < 65536) {
    int g2 = g - 32768;
    int d = g2 >> 7, k = g2 & 127; // M2B[d][k] = sum_c w2[d,c]*mk[c,k]
    float s = 0.f;
#pragma unroll 8
    for (int c = 0; c < 256; ++c)
      s = fmaf(w2[d*256 + c], mk[c*128 + k], s);
    W[OFF_M2B + g2] = s;
  } else if (g < 65664) {
    int k = g - 65536;
    float s = 0.f;
#pragma unroll 8
    for (int d = 0; d < 256; ++d)
      s = fmaf(b1[d], mk[d*128 + k], s);
    W[OFF_BK + k] = s;
  } else if (g < 65664 + 10240) {
    W[OFF_S + (g - 65664)] = 0.f;  // zero s[] and bnacc (contiguous)
  }
}

// ---------------- K1: p = exp(x^T @ M1 + biask); s[b][k] = sum_n p ---------
// grid (64 n-tiles, 16 b), block 256 = 4 waves. Wave: 16 tokens x 128 k.
__global__ __launch_bounds__(256) void k1_logits(
    const float* __restrict__ x, float* __restrict__ W,
    u16* __restrict__ p)
{
  const u16* M1P = (const u16*)((char*)W + OFF_M1P_BYTES);
  const float* biask = W + OFF_BK;
  float* s_glob = W + OFF_S;

  const int tid  = threadIdx.x;
  const int wave = tid >> 6;
  const int lane = tid & 63;
  const int q    = lane >> 4;
  const int col  = lane & 15;
  const int b    = blockIdx.y;
  const int n_base = blockIdx.x * 64 + wave * 16;

  f32x4 acc[8];
#pragma unroll
  for (int t = 0; t < 8; ++t) acc[t] = (f32x4){0.f, 0.f, 0.f, 0.f};

  const float* xptr = x + (size_t)b * CC * NN + (size_t)(q * 8) * NN + n_base + col;

  for (int c0 = 0; c0 < 256; c0 += 32) {
    const float* xk = xptr + (size_t)c0 * NN;
    BF8 af;
#pragma unroll
    for (int j = 0; j < 8; ++j) af.u[j] = f2bf(xk[(size_t)j * NN]);
#pragma unroll
    for (int t = 0; t < 8; ++t) {
      bf16x8 bf = *(const bf16x8*)(M1P + (t*16 + col) * 256 + c0 + q*8);
      acc[t] = __builtin_amdgcn_mfma_f32_16x16x32_bf16(af.v, bf, acc[t], 0, 0, 0);
    }
  }

  // epilogue: bias, exp, bf16 store, per-k wave reduction + atomic
  u16* pb = p + (size_t)b * NN * KK;
#pragma unroll
  for (int t = 0; t < 8; ++t) {
    const float bk = biask[t*16 + col];
    float ps = 0.f;
#pragma unroll
    for (int r = 0; r < 4; ++r) {
      const int n = n_base + q*4 + r;
      float e = __expf(acc[t][r] + bk);
      u16 hb = f2bf(e);
      pb[(size_t)n * KK + t*16 + col] = hb;
      ps += bf2f(hb);   // accumulate the rounded value for consistency
    }
    ps += __shfl_xor(ps, 16);
    ps += __shfl_xor(ps, 32);
    if (lane < 16) atomicAdd(&s_glob[b*128 + t*16 + col], ps);
  }
}

// ---------------- K2: M2s[b][d][k] = M2B/s (bf16); rn[b][n] ----------------
// blocks [0,2048): M2s pack. blocks [2048,3072): rn rowsums (coalesced).
__global__ __launch_bounds__(256) void k2_prep(
    const u16* __restrict__ p, float* __restrict__ W)
{
  __shared__ float sinv[128];
  u16* M2s = (u16*)((char*)W + OFF_M2S_BYTES);
  const float* s_glob = W + OFF_S;
  const int tid = threadIdx.x;

  if (blockIdx.x < 2048) {
    int g = blockIdx.x * 256 + tid;       // [0, 524288)
    int b = g >> 15;
    if (tid < 128) sinv[tid] = 1.0f / s_glob[b*128 + tid];
    __syncthreads();
    int rem = g & 32767;                  // d*128 + k
    M2s[g] = f2bf(W[OFF_M2B + rem] * sinv[g & 127]);
  } else {
    int nb = blockIdx.x - 2048;           // [0, 1024)
    int b  = nb >> 6;
    int n0 = (nb & 63) * 64;
    if (tid < 128) sinv[tid] = 1.0f / s_glob[b*128 + tid];
    __syncthreads();
    const int tx = tid & 3;               // k-quarter (32 k)
    const int ty = tid >> 2;              // token within tile (0..63)
    const int n  = n0 + ty;
    const u16* pr = p + ((size_t)b * NN + n) * KK + tx * 32;
    float t = 0.f;
#pragma unroll
    for (int j = 0; j < 4; ++j) {
      uint4 v = *(const uint4*)(pr + j*8);
      const int k8 = tx*32 + j*8;
      t += bf2f((u16)(v.x & 0xffff)) * sinv[k8+0];
      t += bf2f((u16)(v.x >> 16))    * sinv[k8+1];
      t += bf2f((u16)(v.y & 0xffff)) * sinv[k8+2];
      t += bf2f((u16)(v.y >> 16))    * sinv[k8+3];
      t += bf2f((u16)(v.z & 0xffff)) * sinv[k8+4];
      t += bf2f((u16)(v.z >> 16))    * sinv[k8+5];
      t += bf2f((u16)(v.w & 0xffff)) * sinv[k8+6];
      t += bf2f((u16)(v.w >> 16))    * sinv[k8+7];
    }
    t += __shfl_xor(t, 1);
    t += __shfl_xor(t, 2);
    if (tx == 0) W[OFF_RN + b*4096 + n] = 1.0f / (1e-5f + t);
  }
}

// ---------------- K3: o3 = (p @ M2s^T)*rn + b2 ; BN partials ---------------
// grid (64 n-tiles, 16 b), block 256 = 4 waves. Wave: 16 tokens x 256 d.
// D fragment: row = token (q*4+r), col = d (lane&15) -> float4 token stores.
__global__ __launch_bounds__(256) void k3_attn(
    const u16* __restrict__ p, const float* __restrict__ b2,
    float* __restrict__ W, float* __restrict__ o3)
{
  __shared__ float bn_lds[512];
  const u16* M2s = (const u16*)((char*)W + OFF_M2S_BYTES);
  const float* rn = W + OFF_RN;
  float* bnacc = W + OFF_BN;

  const int tid  = threadIdx.x;
  const int wave = tid >> 6;
  const int lane = tid & 63;
  const int q    = lane >> 4;
  const int col  = lane & 15;
  const int b    = blockIdx.y;
  const int n_base = blockIdx.x * 64 + wave * 16;

  bn_lds[tid] = 0.f; bn_lds[256 + tid] = 0.f;
  __syncthreads();

  f32x4 acc[16];
#pragma unroll
  for (int t = 0; t < 16; ++t) acc[t] = (f32x4){0.f, 0.f, 0.f, 0.f};

  const u16* pb  = p + ((size_t)b * NN + n_base + col) * KK;
  const u16* m2b = M2s + ((size_t)b << 15);

#pragma unroll
  for (int k0 = 0; k0 < 128; k0 += 32) {
    bf16x8 bfp = *(const bf16x8*)(pb + k0 + q*8);
#pragma unroll
    for (int t = 0; t < 16; ++t) {
      bf16x8 am = *(const bf16x8*)(m2b + (t*16 + col) * 128 + k0 + q*8);
      // A = p (m=token), B = M2s (n=d): D row=token, col=d
      acc[t] = __builtin_amdgcn_mfma_f32_16x16x32_bf16(bfp, am, acc[t], 0, 0, 0);
    }
  }

  // epilogue: *rn + b2, float4 token-contiguous stores, cheap BN partials
  const float4 rn4 = *(const float4*)(rn + b*4096 + n_base + q*4);
  float* ob = o3 + (size_t)b * CC * NN;
#pragma unroll
  for (int t = 0; t < 16; ++t) {
    const int d = t*16 + col;
    const float bb = b2[d];
    float4 vv;
    vv.x = fmaf(acc[t][0], rn4.x, bb);
    vv.y = fmaf(acc[t][1], rn4.y, bb);
    vv.z = fmaf(acc[t][2], rn4.z, bb);
    vv.w = fmaf(acc[t][3], rn4.w, bb);
    *(float4*)(ob + (size_t)d * NN + n_base + q*4) = vv;
    float s1 = vv.x + vv.y + vv.z + vv.w;
    float s2 = vv.x*vv.x + vv.y*vv.y + vv.z*vv.z + vv.w*vv.w;
    s1 += __shfl_xor(s1, 16);  s2 += __shfl_xor(s2, 16);
    s1 += __shfl_xor(s1, 32);  s2 += __shfl_xor(s2, 32);
    if (lane < 16) {
      atomicAdd(&bn_lds[d], s1);
      atomicAdd(&bn_lds[256 + d], s2);
    }
  }
  __syncthreads();
  const int rep = blockIdx.x & 15;
  atomicAdd(&bnacc[rep*512 + tid],       bn_lds[tid]);
  atomicAdd(&bnacc[rep*512 + 256 + tid], bn_lds[256 + tid]);
}

// ---------------- K4: finalize BN scale/shift ------------------------------
__global__ __launch_bounds__(256) void k4_fin(
    const float* __restrict__ gamma, const float* __restrict__ beta,
    float* __restrict__ W)
{
  const float* bnacc = W + OFF_BN;
  int d = threadIdx.x;
  float s1 = 0.f, s2 = 0.f;
#pragma unroll
  for (int r = 0; r < 16; ++r) { s1 += bnacc[r*512 + d]; s2 += bnacc[r*512 + 256 + d]; }
  const float invn = 1.0f / 65536.0f;
  float mean = s1 * invn;
  float var = s2 * invn - mean * mean;
  float sc = gamma[d] * rsqrtf(var + 1e-3f);
  W[OFF_SC + d] = sc;
  W[OFF_SH + d] = beta[d] - mean * sc;
}

// ---------------- K5: BN apply + residual + LeakyReLU (in-place on d_out) --
__global__ __launch_bounds__(256) void k5_out(
    const float* __restrict__ x, const float* __restrict__ W,
    float* __restrict__ out)
{
  const float* scale = W + OFF_SC;
  const float* shift = W + OFF_SH;
  size_t gid = ((size_t)blockIdx.x * 256 + threadIdx.x) * 4;
  const int d = (int)((gid >> 12) & 255);
  const float sc = scale[d], sh = shift[d];
  float4 o = *(const float4*)(out + gid);     // o3 stored in d_out (fp32)
  float4 xv = *(const float4*)(x + gid);
  float v0 = fmaf(o.x, sc, sh) + xv.x;
  float v1 = fmaf(o.y, sc, sh) + xv.y;
  float v2 = fmaf(o.z, sc, sh) + xv.z;
  float v3 = fmaf(o.w, sc, sh) + xv.w;
  v0 = (v0 >= 0.f) ? v0 : 0.2f * v0;
  v1 = (v1 >= 0.f) ? v1 : 0.2f * v1;
  v2 = (v2 >= 0.f) ? v2 : 0.2f * v2;
  v3 = (v3 >= 0.f) ? v3 : 0.2f * v3;
  float4 st; st.x = v0; st.y = v1; st.z = v2; st.w = v3;
  *(float4*)(out + gid) = st;
}

extern "C" void kernel_launch(void* const* d_in, const int* in_sizes, int n_in,
                              void* d_out, int out_size, void* d_ws, size_t ws_size,
                              hipStream_t stream)
{
  const float* x  = (const float*)d_in[0];
  const float* w1 = (const float*)d_in[1];
  const float* b1 = (const float*)d_in[2];
  const float* mk = (const float*)d_in[3];
  const float* w2 = (const float*)d_in[4];
  const float* b2 = (const float*)d_in[5];
  const float* gamma = (const float*)d_in[6];
  const float* beta  = (const float*)d_in[7];

  float* W = (float*)d_ws;
  u16* p = (u16*)((char*)d_ws + OFF_P_BYTES);  // exp(logits) bf16 [B][N][K]
  float* o3 = (float*)d_out;   // fp32 [B][C][N] in d_out until K5 rewrites in place
  float* out = (float*)d_out;

  k0_pre<<<dim3(297), dim3(256), 0, stream>>>(w1, b1, mk, w2, W);
  k1_logits<<<dim3(64, 16), dim3(256), 0, stream>>>(x, W, p);
  k2_prep<<<dim3(3072), dim3(256), 0, stream>>>(p, W);
  k3_attn<<<dim3(64, 16), dim3(256), 0, stream>>>(p, b2, W, o3);
  k4_fin<<<dim3(1), dim3(256), 0, stream>>>(gamma, beta, W);
  k5_out<<<dim3(16384), dim3(256), 0, stream>>>(x, W, out);
}

// Round 6
// 225.131 us; speedup vs baseline: 1.4184x; 1.1402x over previous
//
#include <hip/hip_runtime.h>
#include <stdint.h>

typedef unsigned short u16;
typedef unsigned int   u32;
typedef __bf16 bf16_t;
typedef bf16_t bf16x8 __attribute__((ext_vector_type(8)));
typedef float  f32x4  __attribute__((ext_vector_type(4)));

#define BB 16
#define CC 256
#define NN 4096
#define KK 128

// workspace layout (float offsets into W = (float*)d_ws)
#define OFF_M2B  0        // 32768 f: M2B[d][k] = sum_c w2[d,c]*mk[c,k] (fp32)
#define OFF_BK   32768    // 128 f  : biask[k] = sum_d b1[d]*mk[d,k]
#define OFF_S    32896    // 2048 f : s[b][k] (zeroed by K0)
#define OFF_BN   34944    // 16 replicas * 512 f (zeroed by K0)
#define OFF_SC   43136    // 256 f
#define OFF_SH   43392    // 256 f
#define OFF_RN   43648    // 65536 f: rn[b][n] = 1/(1e-5 + rowsum)
#define WS_F_END 109184
#define OFF_M1P_BYTES  (109184*4)                 // M1P[k][c] bf16, 64 KB
#define OFF_M2S_BYTES  (OFF_M1P_BYTES + 65536)    // M2s[b][d][k] bf16, 1 MB
#define OFF_P_BYTES    (OFF_M2S_BYTES + 1048576)  // p bf16 [B][N][K], 16.78 MB

__device__ __forceinline__ float bf2f(u16 h) {
  union { u32 u; float f; } v; v.u = ((u32)h) << 16; return v.f;
}
__device__ __forceinline__ u16 f2bf(float f) {
  union { float f; u32 u; } v; v.f = f;
  u32 r = (v.u + 0x7FFFu + ((v.u >> 16) & 1u)) >> 16;
  return (u16)r;
}

union BF8 { u16 u[8]; bf16x8 v; };

// ---------------- K0: M1P (bf16 packed), M2B, biask; zero s/bn --------------
__global__ __launch_bounds__(256) void k0_pre(
    const float* __restrict__ w1, const float* __restrict__ b1,
    const float* __restrict__ mk, const float* __restrict__ w2,
    float* __restrict__ W)
{
  u16* M1P = (u16*)((char*)W + OFF_M1P_BYTES);
  int g = blockIdx.x * 256 + threadIdx.x;
  if (g < 32768) {
    int k = g >> 8, c = g & 255;   // M1P[k][c] = sum_d w1[d,c]*mk[d,k]
    float s = 0.f;
#pragma unroll 8
    for (int d = 0; d < 256; ++d)
      s = fmaf(w1[d*256 + c], mk[d*128 + k], s);
    M1P[g] = f2bf(s);
  } else if (g < 65536) {
    int g2 = g - 32768;
    int d = g2 >> 7, k = g2 & 127; // M2B[d][k] = sum_c w2[d,c]*mk[c,k]
    float s = 0.f;
#pragma unroll 8
    for (int c = 0; c < 256; ++c)
      s = fmaf(w2[d*256 + c], mk[c*128 + k], s);
    W[OFF_M2B + g2] = s;
  } else if (g < 65664) {
    int k = g - 65536;
    float s = 0.f;
#pragma unroll 8
    for (int d = 0; d < 256; ++d)
      s = fmaf(b1[d], mk[d*128 + k], s);
    W[OFF_BK + k] = s;
  } else if (g < 65664 + 10240) {
    W[OFF_S + (g - 65664)] = 0.f;  // zero s[] and bnacc (contiguous)
  }
}

// ---------------- K1: p = exp(x^T @ M1 + biask); s[b][k] = sum_n p ---------
// grid (64 n-tiles, 16 b), block 256 = 4 waves. Wave: 16 tokens x 128 k.
__global__ __launch_bounds__(256) void k1_logits(
    const float* __restrict__ x, float* __restrict__ W,
    u16* __restrict__ p)
{
  const u16* M1P = (const u16*)((char*)W + OFF_M1P_BYTES);
  const float* biask = W + OFF_BK;
  float* s_glob = W + OFF_S;

  const int tid  = threadIdx.x;
  const int wave = tid >> 6;
  const int lane = tid & 63;
  const int q    = lane >> 4;
  const int col  = lane & 15;
  const int b    = blockIdx.y;
  const int n_base = blockIdx.x * 64 + wave * 16;

  f32x4 acc[8];
#pragma unroll
  for (int t = 0; t < 8; ++t) acc[t] = (f32x4){0.f, 0.f, 0.f, 0.f};

  const float* xptr = x + (size_t)b * CC * NN + (size_t)(q * 8) * NN + n_base + col;

  for (int c0 = 0; c0 < 256; c0 += 32) {
    const float* xk = xptr + (size_t)c0 * NN;
    BF8 af;
#pragma unroll
    for (int j = 0; j < 8; ++j) af.u[j] = f2bf(xk[(size_t)j * NN]);
#pragma unroll
    for (int t = 0; t < 8; ++t) {
      bf16x8 bf = *(const bf16x8*)(M1P + (t*16 + col) * 256 + c0 + q*8);
      acc[t] = __builtin_amdgcn_mfma_f32_16x16x32_bf16(af.v, bf, acc[t], 0, 0, 0);
    }
  }

  // epilogue: bias, exp, bf16 store, per-k wave reduction + atomic
  u16* pb = p + (size_t)b * NN * KK;
#pragma unroll
  for (int t = 0; t < 8; ++t) {
    const float bk = biask[t*16 + col];
    float ps = 0.f;
#pragma unroll
    for (int r = 0; r < 4; ++r) {
      const int n = n_base + q*4 + r;
      float e = __expf(acc[t][r] + bk);
      u16 hb = f2bf(e);
      pb[(size_t)n * KK + t*16 + col] = hb;
      ps += bf2f(hb);   // accumulate the rounded value for consistency
    }
    ps += __shfl_xor(ps, 16);
    ps += __shfl_xor(ps, 32);
    if (lane < 16) atomicAdd(&s_glob[b*128 + t*16 + col], ps);
  }
}

// ---------------- K2: M2s[b][d][k] = M2B/s (bf16); rn[b][n] ----------------
// blocks [0,2048): M2s pack. blocks [2048,3072): rn rowsums (coalesced).
__global__ __launch_bounds__(256) void k2_prep(
    const u16* __restrict__ p, float* __restrict__ W)
{
  __shared__ float sinv[128];
  u16* M2s = (u16*)((char*)W + OFF_M2S_BYTES);
  const float* s_glob = W + OFF_S;
  const int tid = threadIdx.x;

  if (blockIdx.x < 2048) {
    int g = blockIdx.x * 256 + tid;       // [0, 524288)
    int b = g >> 15;
    if (tid < 128) sinv[tid] = 1.0f / s_glob[b*128 + tid];
    __syncthreads();
    int rem = g & 32767;                  // d*128 + k
    M2s[g] = f2bf(W[OFF_M2B + rem] * sinv[g & 127]);
  } else {
    int nb = blockIdx.x - 2048;           // [0, 1024)
    int b  = nb >> 6;
    int n0 = (nb & 63) * 64;
    if (tid < 128) sinv[tid] = 1.0f / s_glob[b*128 + tid];
    __syncthreads();
    const int tx = tid & 3;               // k-quarter (32 k)
    const int ty = tid >> 2;              // token within tile (0..63)
    const int n  = n0 + ty;
    const u16* pr = p + ((size_t)b * NN + n) * KK + tx * 32;
    float t = 0.f;
#pragma unroll
    for (int j = 0; j < 4; ++j) {
      uint4 v = *(const uint4*)(pr + j*8);
      const int k8 = tx*32 + j*8;
      t += bf2f((u16)(v.x & 0xffff)) * sinv[k8+0];
      t += bf2f((u16)(v.x >> 16))    * sinv[k8+1];
      t += bf2f((u16)(v.y & 0xffff)) * sinv[k8+2];
      t += bf2f((u16)(v.y >> 16))    * sinv[k8+3];
      t += bf2f((u16)(v.z & 0xffff)) * sinv[k8+4];
      t += bf2f((u16)(v.z >> 16))    * sinv[k8+5];
      t += bf2f((u16)(v.w & 0xffff)) * sinv[k8+6];
      t += bf2f((u16)(v.w >> 16))    * sinv[k8+7];
    }
    t += __shfl_xor(t, 1);
    t += __shfl_xor(t, 2);
    if (tx == 0) W[OFF_RN + b*4096 + n] = 1.0f / (1e-5f + t);
  }
}

// ---------------- K3: o3 = (p @ M2s^T)*rn + b2 ; BN partials ---------------
// grid (64 n-tiles, 16 b), block 256 = 4 waves. Wave: 64 tokens x 64 d
// (4 token-groups x 4 d-tiles) -> loads:MFMA = 1:4, am slice 16KB (L1-fit).
__global__ __launch_bounds__(256, 4) void k3_attn(
    const u16* __restrict__ p, const float* __restrict__ b2,
    float* __restrict__ W, float* __restrict__ o3)
{
  const u16* M2s = (const u16*)((char*)W + OFF_M2S_BYTES);
  const float* rn = W + OFF_RN;
  float* bnacc = W + OFF_BN;

  const int tid  = threadIdx.x;
  const int wave = tid >> 6;
  const int lane = tid & 63;
  const int q    = lane >> 4;
  const int col  = lane & 15;
  const int b    = blockIdx.y;
  const int n_base = blockIdx.x * 64;
  const int d_base = wave * 64;

  f32x4 acc[4][4];
#pragma unroll
  for (int g = 0; g < 4; ++g)
#pragma unroll
    for (int t = 0; t < 4; ++t) acc[g][t] = (f32x4){0.f, 0.f, 0.f, 0.f};

  const u16* pb0 = p + ((size_t)b * NN + n_base + col) * KK;
  const u16* m2b = M2s + ((size_t)b << 15) + (size_t)(d_base + col) * 128;

#pragma unroll
  for (int k0 = 0; k0 < 128; k0 += 32) {
    bf16x8 bfp[4], amv[4];
#pragma unroll
    for (int g = 0; g < 4; ++g)
      bfp[g] = *(const bf16x8*)(pb0 + (size_t)(g*16)*KK + k0 + q*8);
#pragma unroll
    for (int t = 0; t < 4; ++t)
      amv[t] = *(const bf16x8*)(m2b + (size_t)(t*16)*128 + k0 + q*8);
#pragma unroll
    for (int g = 0; g < 4; ++g)
#pragma unroll
      for (int t = 0; t < 4; ++t)
        // A = p (m=token), B = M2s (n=d): D row=token, col=d
        acc[g][t] = __builtin_amdgcn_mfma_f32_16x16x32_bf16(bfp[g], amv[t], acc[g][t], 0, 0, 0);
  }

  // epilogue: *rn + b2, float4 token-contiguous stores, register-folded BN
  float* ob = o3 + (size_t)b * CC * NN;
  float s1t[4] = {0.f, 0.f, 0.f, 0.f};
  float s2t[4] = {0.f, 0.f, 0.f, 0.f};
#pragma unroll
  for (int g = 0; g < 4; ++g) {
    const float4 rn4 = *(const float4*)(rn + b*4096 + n_base + g*16 + q*4);
#pragma unroll
    for (int t = 0; t < 4; ++t) {
      const int d = d_base + t*16 + col;
      const float bb = b2[d];
      float4 vv;
      vv.x = fmaf(acc[g][t][0], rn4.x, bb);
      vv.y = fmaf(acc[g][t][1], rn4.y, bb);
      vv.z = fmaf(acc[g][t][2], rn4.z, bb);
      vv.w = fmaf(acc[g][t][3], rn4.w, bb);
      *(float4*)(ob + (size_t)d * NN + n_base + g*16 + q*4) = vv;
      s1t[t] += vv.x + vv.y + vv.z + vv.w;
      s2t[t] += vv.x*vv.x + vv.y*vv.y + vv.z*vv.z + vv.w*vv.w;
    }
  }
  const int rep = blockIdx.x & 15;
#pragma unroll
  for (int t = 0; t < 4; ++t) {
    float s1 = s1t[t], s2 = s2t[t];
    s1 += __shfl_xor(s1, 16);  s2 += __shfl_xor(s2, 16);
    s1 += __shfl_xor(s1, 32);  s2 += __shfl_xor(s2, 32);
    if (lane < 16) {
      const int d = d_base + t*16 + col;
      atomicAdd(&bnacc[rep*512 + d], s1);
      atomicAdd(&bnacc[rep*512 + 256 + d], s2);
    }
  }
}

// ---------------- K4: finalize BN scale/shift ------------------------------
__global__ __launch_bounds__(256) void k4_fin(
    const float* __restrict__ gamma, const float* __restrict__ beta,
    float* __restrict__ W)
{
  const float* bnacc = W + OFF_BN;
  int d = threadIdx.x;
  float s1 = 0.f, s2 = 0.f;
#pragma unroll
  for (int r = 0; r < 16; ++r) { s1 += bnacc[r*512 + d]; s2 += bnacc[r*512 + 256 + d]; }
  const float invn = 1.0f / 65536.0f;
  float mean = s1 * invn;
  float var = s2 * invn - mean * mean;
  float sc = gamma[d] * rsqrtf(var + 1e-3f);
  W[OFF_SC + d] = sc;
  W[OFF_SH + d] = beta[d] - mean * sc;
}

// ---------------- K5: BN apply + residual + LeakyReLU (in-place on d_out) --
__global__ __launch_bounds__(256) void k5_out(
    const float* __restrict__ x, const float* __restrict__ W,
    float* __restrict__ out)
{
  const float* scale = W + OFF_SC;
  const float* shift = W + OFF_SH;
  size_t gid = ((size_t)blockIdx.x * 256 + threadIdx.x) * 4;
  const int d = (int)((gid >> 12) & 255);
  const float sc = scale[d], sh = shift[d];
  float4 o = *(const float4*)(out + gid);     // o3 stored in d_out (fp32)
  float4 xv = *(const float4*)(x + gid);
  float v0 = fmaf(o.x, sc, sh) + xv.x;
  float v1 = fmaf(o.y, sc, sh) + xv.y;
  float v2 = fmaf(o.z, sc, sh) + xv.z;
  float v3 = fmaf(o.w, sc, sh) + xv.w;
  v0 = (v0 >= 0.f) ? v0 : 0.2f * v0;
  v1 = (v1 >= 0.f) ? v1 : 0.2f * v1;
  v2 = (v2 >= 0.f) ? v2 : 0.2f * v2;
  v3 = (v3 >= 0.f) ? v3 : 0.2f * v3;
  float4 st; st.x = v0; st.y = v1; st.z = v2; st.w = v3;
  *(float4*)(out + gid) = st;
}

extern "C" void kernel_launch(void* const* d_in, const int* in_sizes, int n_in,
                              void* d_out, int out_size, void* d_ws, size_t ws_size,
                              hipStream_t stream)
{
  const float* x  = (const float*)d_in[0];
  const float* w1 = (const float*)d_in[1];
  const float* b1 = (const float*)d_in[2];
  const float* mk = (const float*)d_in[3];
  const float* w2 = (const float*)d_in[4];
  const float* b2 = (const float*)d_in[5];
  const float* gamma = (const float*)d_in[6];
  const float* beta  = (const float*)d_in[7];

  float* W = (float*)d_ws;
  u16* p = (u16*)((char*)d_ws + OFF_P_BYTES);  // exp(logits) bf16 [B][N][K]
  float* o3 = (float*)d_out;   // fp32 [B][C][N] in d_out until K5 rewrites in place
  float* out = (float*)d_out;

  k0_pre<<<dim3(297), dim3(256), 0, stream>>>(w1, b1, mk, w2, W);
  k1_logits<<<dim3(64, 16), dim3(256), 0, stream>>>(x, W, p);
  k2_prep<<<dim3(3072), dim3(256), 0, stream>>>(p, W);
  k3_attn<<<dim3(64, 16), dim3(256), 0, stream>>>(p, b2, W, o3);
  k4_fin<<<dim3(1), dim3(256), 0, stream>>>(gamma, beta, W);
  k5_out<<<dim3(16384), dim3(256), 0, stream>>>(x, W, out);
}